// Round 6
// baseline (284.381 us; speedup 1.0000x reference)
//
#include <hip/hip_runtime.h>

// SNN forward, all GEMM operands pre-swizzled to LDS-image order so every
// global_load_lds stages a contiguous 1 KB per wave (no gather).
//   Xt  [n][c 4][kk 8][tl 128][k 32]   f16   (t padded to 512, zeros)
//   W1t [ht 8][kk 8][hl 128][k 32]     f16 hi+lo
//   s1sw[mtile 250][kk 32][ml 128][hq 32] f16  (gemm2 A staging order)
//   W2t [kk 32][o 32][k 32]            f16 hi+lo
// f16 split-2: W = hi + lo, residual ~2^-24 => fp32-grade MFMA results.
// Layer-1 kernel is wave-specialized + software-pipelined: waves 0-3 GEMM
// chunk p while waves 4-5 scan chunk p-1 between the same barriers.

#define NN 64
#define II 256
#define HH 1024
#define OO 18
#define TT 500

#define D_SR 0.9048374180359595f   // exp(-1/10)
#define C_SR 0.27182818284590454f  // e/10
#define D_RF 0.36787944117144233f  // exp(-1)
#define C_RF 2.718281828459045f    // e
#define THETA 10.0f
#define REFS (-20.0f)

typedef _Float16 f16;
typedef _Float16 f16x2 __attribute__((ext_vector_type(2)));
typedef _Float16 f16x8 __attribute__((ext_vector_type(8)));
typedef float f32x4 __attribute__((ext_vector_type(4)));

__device__ __forceinline__ void gl2lds16(const void* g, void* l) {
    __builtin_amdgcn_global_load_lds(
        (const __attribute__((address_space(1))) void*)g,
        (__attribute__((address_space(3))) void*)l, 16, 0, 0);
}

// ---------------- prep: X [N][I][T] f32 -> Xt tiled f16 ---------------------
__launch_bounds__(256)
__global__ void prep_xt(const float* __restrict__ X, f16* __restrict__ Xt) {
    __shared__ float tile[128 * 129];
    const int c = blockIdx.x, n = blockIdx.y;
    const int t0 = c * 128;
    const int tid = threadIdx.x;
    const int tx = tid & 63, rw = tid >> 6;
    const int q = tid & 3, tl6 = tid >> 2;

    for (int ih = 0; ih < 2; ++ih) {
        const float* Xn = X + ((size_t)n * II + ih * 128) * TT;
#pragma unroll 4
        for (int rep = 0; rep < 32; ++rep) {
            int r = rep * 4 + rw;
            int t = 2 * tx;
            float v0 = 0.f, v1 = 0.f;
            if (t0 + 128 <= TT) {
                float2 v = *(const float2*)(Xn + (size_t)r * TT + t0 + t);
                v0 = v.x; v1 = v.y;
            } else {
                if (t0 + t < TT)     v0 = Xn[(size_t)r * TT + t0 + t];
                if (t0 + t + 1 < TT) v1 = Xn[(size_t)r * TT + t0 + t + 1];
            }
            tile[t * 129 + r] = v0;
            tile[(t + 1) * 129 + r] = v1;
        }
        __syncthreads();
#pragma unroll
        for (int kkl = 0; kkl < 4; ++kkl)
#pragma unroll
            for (int hp = 0; hp < 2; ++hp) {
                int row = hp * 64 + tl6;
                f16x8 h;
#pragma unroll
                for (int e = 0; e < 8; ++e)
                    h[e] = (f16)tile[row * 129 + kkl * 32 + q * 8 + e];
                size_t dst = ((((size_t)(n * 4 + c) * 8 + ih * 4 + kkl) * 128 + row) * 32) + q * 8;
                *(f16x8*)(Xt + dst) = h;
            }
        __syncthreads();
    }
}

// ---------------- prep: W1 -> W1t hi/lo tiled -------------------------------
__launch_bounds__(256)
__global__ void prep_w1t(const float* __restrict__ W1, f16* __restrict__ Wh,
                         f16* __restrict__ Wl) {
    int idx = blockIdx.x * 256 + threadIdx.x;  // < 32768
    int q = idx & 3, hl = (idx >> 2) & 127, kk = (idx >> 9) & 7, ht = idx >> 12;
    const float* src = W1 + (size_t)(ht * 128 + hl) * II + kk * 32 + q * 8;
    f16x8 h, l;
#pragma unroll
    for (int e = 0; e < 8; ++e) {
        float w = src[e];
        f16 hh = (f16)w;
        h[e] = hh;
        l[e] = (f16)(w - (float)hh);
    }
    *(f16x8*)(Wh + (size_t)idx * 8) = h;
    *(f16x8*)(Wl + (size_t)idx * 8) = l;
}

// ---------------- prep: W2 -> W2t hi/lo tiled [kk][o 32][k 32] --------------
__launch_bounds__(256)
__global__ void prep_w2t(const float* __restrict__ W2, f16* __restrict__ Wh,
                         f16* __restrict__ Wl) {
    int idx = blockIdx.x * 256 + threadIdx.x;  // < 4096
    int q = idx & 3, o = (idx >> 2) & 31, kk = idx >> 7;
    f16x8 h, l;
#pragma unroll
    for (int e = 0; e < 8; ++e) {
        float w = (o < OO) ? W2[(size_t)o * HH + kk * 32 + q * 8 + e] : 0.f;
        f16 hh = (f16)w;
        h[e] = hh;
        l[e] = (f16)(w - (float)hh);
    }
    *(f16x8*)(Wh + (size_t)idx * 8) = h;
    *(f16x8*)(Wl + (size_t)idx * 8) = l;
}

// ---------------- FUSED layer 1, pipelined ----------------------------------
// grid (8, 64), 512 thr (8 waves). 5 periods: GEMM chunk p on waves 0-3,
// scan chunk p-1 on waves 4-5 (16 steps per K-slot, same barrier sequence),
// pack chunk p-1 on waves 4-7, then epilogue p -> yb (single buffer;
// pack reads before epilogue writes). Scan state persists in wave-4/5 regs.
__launch_bounds__(512)
__global__ void gemm1_scan1(const f16* __restrict__ Xt, const f16* __restrict__ Wh,
                            const f16* __restrict__ Wl, f16* __restrict__ S1sw) {
    __shared__ __align__(16) f16 As[128 * 32];   // 8 KB
    __shared__ __align__(16) f16 Bh[128 * 32];   // 8 KB
    __shared__ __align__(16) f16 Bl[128 * 32];   // 8 KB
    __shared__ float yb[128 * 129];              // 66,048 B

    const int tid = threadIdx.x;
    const int wave = tid >> 6, lane = tid & 63;

    // XCD swizzle: the 8 h-tiles of one n share an XCD
    const int f = blockIdx.y * 8 + blockIdx.x;
    const int x = f & 7, g = f >> 3;
    const int n = x * 8 + (g & 7);
    const int ht = g >> 3;
    const int h0g = ht * 128;

    const f16* Abase = Xt + (size_t)(n * 4) * 8 * 4096;
    const f16* Bhbase = Wh + (size_t)ht * 8 * 4096;
    const f16* Blbase = Wl + (size_t)ht * 8 * 4096;
    const int woff = wave * 1024 + lane * 8;

    f16* lA = As + wave * 1024;
    f16* lBh = Bh + wave * 1024;
    f16* lBl = Bl + wave * 1024;

    const int wm = wave & 1, wn = (wave >> 1) & 1;
    const int fr = lane & 15, kq = lane >> 4;

    const bool gemmw = (wave < 4);
    const bool scanw = (tid >= 256 && tid < 384);
    const int sw = tid - 256;  // scan channel (valid when scanw)

    float p1 = 0.f, a1 = 0.f, p2 = 0.f, a2 = 0.f;  // scan state (waves 4-5)

    for (int p = 0; p < 5; ++p) {
        const int TS = (p == 4) ? 116 : 128;  // length of scan chunk p-1

        float vcur[16];
        if (scanw && p >= 1) {
#pragma unroll
            for (int j = 0; j < 16; ++j) vcur[j] = yb[j * 129 + sw];
        }

        f32x4 acc[4][4] = {};
        for (int kk = 0; kk < 8; ++kk) {
            if (gemmw && p < 4) {
                const f16* a = Abase + (size_t)(p * 8 + kk) * 4096 + woff;
                const f16* bh = Bhbase + (size_t)kk * 4096 + woff;
                const f16* bl = Blbase + (size_t)kk * 4096 + woff;
                gl2lds16(a, lA);
                gl2lds16(a + 512, lA + 512);
                gl2lds16(bh, lBh);
                gl2lds16(bh + 512, lBh + 512);
                gl2lds16(bl, lBl);
                gl2lds16(bl + 512, lBl + 512);
            }
            __syncthreads();
            if (gemmw && p < 4) {
                f16x8 av[4], bhv[4], blv[4];
#pragma unroll
                for (int i = 0; i < 4; ++i) {
                    av[i]  = *(const f16x8*)(As + (wm * 64 + i * 16 + fr) * 32 + kq * 8);
                    bhv[i] = *(const f16x8*)(Bh + (wn * 64 + i * 16 + fr) * 32 + kq * 8);
                    blv[i] = *(const f16x8*)(Bl + (wn * 64 + i * 16 + fr) * 32 + kq * 8);
                }
#pragma unroll
                for (int i = 0; i < 4; ++i)
#pragma unroll
                    for (int j = 0; j < 4; ++j) {
                        acc[i][j] = __builtin_amdgcn_mfma_f32_16x16x32_f16(av[i], bhv[j], acc[i][j], 0, 0, 0);
                        acc[i][j] = __builtin_amdgcn_mfma_f32_16x16x32_f16(av[i], blv[j], acc[i][j], 0, 0, 0);
                    }
            } else if (scanw && p >= 1) {
                const int tb = kk * 16;
                float vnext[16];
                if (kk < 7) {
#pragma unroll
                    for (int j = 0; j < 16; ++j)
                        vnext[j] = yb[(tb + 16 + j) * 129 + sw];
                }
#pragma unroll
                for (int j = 0; j < 16; ++j) {
                    int t = tb + j;
                    if (t < TS) {
                        float xv = vcur[j];
                        a1 = D_SR * (a1 + p1);
                        p1 = D_SR * p1 + xv;
                        float ut = C_SR * a1;
                        a2 = D_RF * (a2 + p2);
                        float u = ut + C_RF * a2;
                        float s = (u >= THETA) ? 1.0f : 0.0f;
                        p2 = D_RF * p2 + REFS * s;
                        yb[t * 129 + sw] = s;
                    }
                }
                if (kk < 7) {
#pragma unroll
                    for (int j = 0; j < 16; ++j) vcur[j] = vnext[j];
                }
            }
            __syncthreads();
        }

        // pack chunk p-1 (waves 4-7) -- reads yb BEFORE epilogue overwrites
        if (p >= 1 && tid >= 256) {
            const int t0c = (p - 1) * 128;
            const int lt = tid - 256;
#pragma unroll 4
            for (int rep = 0; rep < 32; ++rep) {
                int e = rep * 256 + lt;
                int row = e >> 6, cp = e & 63;
                if (row < TS) {
                    float v0 = yb[row * 129 + 2 * cp];
                    float v1 = yb[row * 129 + 2 * cp + 1];
                    int m = n * TT + t0c + row;
                    int mtile = m >> 7, ml = m & 127;
                    int h = h0g + 2 * cp;
                    int kk2 = h >> 5, hq = h & 31;
                    f16x2 h2 = {(f16)v0, (f16)v1};
                    *(f16x2*)(S1sw + (((size_t)mtile * 32 + kk2) * 128 + ml) * 32 + hq) = h2;
                }
            }
        }
        __syncthreads();

        // epilogue chunk p -> yb (waves 0-3)
        if (gemmw && p < 4) {
#pragma unroll
            for (int i = 0; i < 4; ++i)
#pragma unroll
                for (int j = 0; j < 4; ++j) {
                    int tr = wm * 64 + i * 16 + kq * 4;
                    int hc = wn * 64 + j * 16 + fr;
#pragma unroll
                    for (int r = 0; r < 4; ++r)
                        yb[(tr + r) * 129 + hc] = acc[i][j][r];
                }
        }
        __syncthreads();
    }
}

// ---------------- GEMM2 (MFMA, split-f16): y2 = s1 * W2^T -------------------
__launch_bounds__(256)
__global__ void gemm2_mfma(const f16* __restrict__ S1sw, const f16* __restrict__ W2h,
                           const f16* __restrict__ W2l, float* __restrict__ Y2) {
    __shared__ __align__(16) f16 As[128 * 32];
    __shared__ __align__(16) f16 Bh[32 * 32];
    __shared__ __align__(16) f16 Bl[32 * 32];

    const int tid = threadIdx.x;
    const int wave = tid >> 6, lane = tid & 63;
    const int m0 = blockIdx.x * 128;
    const int fr = lane & 15, kq = lane >> 4;

    f16* lA = As + wave * 1024;
    f16* lB = (wave < 2 ? Bh : Bl) + (wave & 1) * 512;

    f32x4 acc[2][2] = {};

    for (int kk = 0; kk < 32; ++kk) {
        const f16* a = S1sw + ((size_t)blockIdx.x * 32 + kk) * 4096 + wave * 1024 + lane * 8;
        gl2lds16(a, lA);
        gl2lds16(a + 512, lA + 512);
        const f16* bsrc = (wave < 2 ? W2h : W2l) + (size_t)kk * 1024 + (wave & 1) * 512 + lane * 8;
        gl2lds16(bsrc, lB);
        __syncthreads();

        f16x8 av[2], bhv[2], blv[2];
#pragma unroll
        for (int i = 0; i < 2; ++i) {
            av[i]  = *(const f16x8*)(As + (wave * 32 + i * 16 + fr) * 32 + kq * 8);
            bhv[i] = *(const f16x8*)(Bh + (i * 16 + fr) * 32 + kq * 8);
            blv[i] = *(const f16x8*)(Bl + (i * 16 + fr) * 32 + kq * 8);
        }
#pragma unroll
        for (int i = 0; i < 2; ++i)
#pragma unroll
            for (int j = 0; j < 2; ++j) {
                acc[i][j] = __builtin_amdgcn_mfma_f32_16x16x32_f16(av[i], bhv[j], acc[i][j], 0, 0, 0);
                acc[i][j] = __builtin_amdgcn_mfma_f32_16x16x32_f16(av[i], blv[j], acc[i][j], 0, 0, 0);
            }
        __syncthreads();
    }

#pragma unroll
    for (int i = 0; i < 2; ++i)
#pragma unroll
        for (int j = 0; j < 2; ++j) {
            int rbase = m0 + wave * 32 + i * 16 + kq * 4;
            int cc = j * 16 + fr;
            float* p = Y2 + (size_t)rbase * 32 + cc;
#pragma unroll
            for (int r = 0; r < 4; ++r)
                p[(size_t)r * 32] = acc[i][j][r];
        }
}

// ---------------- scan2: y2 [N*T][32] f32 -> out [N][O][T] ------------------
#define PF2 16
__launch_bounds__(64)
__global__ void scan2_k(const float* __restrict__ Y2, float* __restrict__ Out) {
    __shared__ float sb[OO * TT];
    const int n = blockIdx.x, lane = threadIdx.x;
    const float* y = Y2 + (size_t)n * TT * 32;
    const bool act = (lane < 32);

    float p1 = 0.f, a1 = 0.f, p2 = 0.f, a2 = 0.f;
    float buf[PF2];
#pragma unroll
    for (int j = 0; j < PF2; ++j) buf[j] = act ? y[j * 32 + lane] : 0.f;

    int t = 0;
    for (; t + PF2 <= TT; t += PF2) {
#pragma unroll
        for (int j = 0; j < PF2; ++j) {
            float x = buf[j];
            buf[j] = (act && t + j + PF2 < TT) ? y[(t + j + PF2) * 32 + lane] : 0.f;
            a1 = D_SR * (a1 + p1);
            p1 = D_SR * p1 + x;
            float ut = C_SR * a1;
            a2 = D_RF * (a2 + p2);
            float u = ut + C_RF * a2;
            float s = (u >= THETA) ? 1.0f : 0.0f;
            p2 = D_RF * p2 + REFS * s;
            if (lane < OO) sb[lane * TT + t + j] = s;
        }
    }
#pragma unroll
    for (int j = 0; j < PF2; ++j) {
        if (t + j < TT) {
            float x = buf[j];
            a1 = D_SR * (a1 + p1);
            p1 = D_SR * p1 + x;
            float ut = C_SR * a1;
            a2 = D_RF * (a2 + p2);
            float u = ut + C_RF * a2;
            float s = (u >= THETA) ? 1.0f : 0.0f;
            p2 = D_RF * p2 + REFS * s;
            if (lane < OO) sb[lane * TT + t + j] = s;
        }
    }
    __syncthreads();
    float* on = Out + (size_t)n * OO * TT;
    for (int e = lane; e < OO * TT; e += 64) on[e] = sb[e];
}

extern "C" void kernel_launch(void* const* d_in, const int* in_sizes, int n_in,
                              void* d_out, int out_size, void* d_ws, size_t ws_size,
                              hipStream_t stream) {
    const float* X  = (const float*)d_in[0];
    const float* W1 = (const float*)d_in[1];
    const float* W2 = (const float*)d_in[2];
    float* out = (float*)d_out;

    const size_t s_s1 = (size_t)250 * 32 * 128 * 32 * 2;   // 65,536,000
    const size_t s_Xt = (size_t)NN * 4 * 8 * 128 * 32 * 2; // 16,777,216
    const size_t s_W  = (size_t)8 * 8 * 128 * 32 * 2;      //    524,288 (x2)
    const size_t s_W2 = (size_t)32 * 32 * 32 * 2;          //     65,536 (x2)

    char* w = (char*)d_ws;
    f16*   s1sw = (f16*)w;  w += s_s1;
    f16*   Xt   = (f16*)w;  w += s_Xt;
    f16*   W1h  = (f16*)w;  w += s_W;
    f16*   W1l  = (f16*)w;  w += s_W;
    f16*   W2h  = (f16*)w;  w += s_W2;
    f16*   W2l  = (f16*)w;  w += s_W2;
    float* y2   = (float*)w;

    prep_xt<<<dim3(4, NN), 256, 0, stream>>>(X, Xt);
    prep_w1t<<<128, 256, 0, stream>>>(W1, W1h, W1l);
    prep_w2t<<<16, 256, 0, stream>>>(W2, W2h, W2l);

    gemm1_scan1<<<dim3(8, NN), 512, 0, stream>>>(Xt, W1h, W1l, s1sw);

    gemm2_mfma<<<250, 256, 0, stream>>>(s1sw, W2h, W2l, y2);
    scan2_k<<<NN, 64, 0, stream>>>(y2, out);
}

// Round 7
// 223.370 us; speedup vs baseline: 1.2731x; 1.2731x over previous
//
#include <hip/hip_runtime.h>

// SNN forward: [GEMM1+scan1 fused, 64x64 tiles, 4 blocks/CU] -> GEMM2 -> scan2
// f16 split-2: W = hi + lo (both f16), residual ~2^-24 => fp32-grade MFMA.
// X and spikes are exact in f16.
//   Xb  [n*t][I] f16 row-major
//   W1h/l [H][I] f16
//   s1b [n*t][H] f16
//   W2h/l [32 padded][H] f16

#define NN 64
#define II 256
#define HH 1024
#define OO 18
#define TT 500

#define D_SR 0.9048374180359595f   // exp(-1/10)
#define C_SR 0.27182818284590454f  // e/10
#define D_RF 0.36787944117144233f  // exp(-1)
#define C_RF 2.718281828459045f    // e
#define THETA 10.0f
#define REFS (-20.0f)

typedef _Float16 f16;
typedef _Float16 f16x2 __attribute__((ext_vector_type(2)));
typedef _Float16 f16x8 __attribute__((ext_vector_type(8)));
typedef float f32x4 __attribute__((ext_vector_type(4)));

__device__ __forceinline__ void gl2lds16(const void* g, void* l) {
    __builtin_amdgcn_global_load_lds(
        (const __attribute__((address_space(1))) void*)g,
        (__attribute__((address_space(3))) void*)l, 16, 0, 0);
}

// ---------------- prep: X [N][I][T] f32 -> Xb [N*T][I] f16 (transpose) -----
__launch_bounds__(256)
__global__ void prep_x(const float* __restrict__ X, f16* __restrict__ Xb) {
    __shared__ float tile[64][65];
    const int n = blockIdx.z, i0 = blockIdx.y * 64, t0 = blockIdx.x * 64;
    const int tx = threadIdx.x & 63, q = threadIdx.x >> 6;
    const float* Xn = X + (size_t)n * II * TT;
#pragma unroll 4
    for (int j = 0; j < 16; ++j) {
        int il = j * 4 + q;
        int t = t0 + tx;
        tile[il][tx] = (t < TT) ? Xn[(size_t)(i0 + il) * TT + t] : 0.f;
    }
    __syncthreads();
#pragma unroll 4
    for (int j = 0; j < 16; ++j) {
        int tl = j * 4 + q;
        int t = t0 + tl;
        if (t < TT)
            Xb[((size_t)n * TT + t) * II + i0 + tx] = (f16)tile[tx][tl];
    }
}

// ---------------- prep: W1 -> f16 hi/lo [H][I] ------------------------------
__launch_bounds__(256)
__global__ void prep_w1(const float* __restrict__ W1, f16* __restrict__ Wh,
                        f16* __restrict__ Wl) {
    int idx = blockIdx.x * 256 + threadIdx.x;
    float w = W1[idx];
    f16 h = (f16)w;
    f16 l = (f16)(w - (float)h);
    Wh[idx] = h;
    Wl[idx] = l;
}

// ---------------- prep: W2 -> f16 hi/lo [32 padded][H] ----------------------
__launch_bounds__(256)
__global__ void prep_w2(const float* __restrict__ W2, f16* __restrict__ Wh,
                        f16* __restrict__ Wl) {
    int idx = blockIdx.x * 256 + threadIdx.x;
    int o = idx >> 10;
    float w = (o < OO) ? W2[idx] : 0.f;
    f16 h = (f16)w;
    f16 l = (f16)(w - (float)h);
    Wh[idx] = h;
    Wl[idx] = l;
}

// ---------------- FUSED layer 1: 64x64 tiles, 4 blocks/CU -------------------
// grid (16 ht, 64 n), 256 thr (4 waves). Per block: 8 chunks of 64 t.
// Chunk: K-loop (8x BK=32 MFMA) -> epilogue->yb -> scan (64 lanes) -> pack.
// LDS union: staging 12 KB / yb 16.9 KB. Scan state lives in tid<64 regs.
#define CT1 64
__launch_bounds__(256, 4)
__global__ void gemm1_scan1(const f16* __restrict__ Xb, const f16* __restrict__ Wh,
                            const f16* __restrict__ Wl, f16* __restrict__ S1) {
    __shared__ __align__(16) char smem[CT1 * 66 * 4];  // 16,896 B
    f16* As = (f16*)smem;                 // 64x32 f16 = 4 KB
    f16* Bh = (f16*)(smem + 4096);        // 4 KB
    f16* Bl = (f16*)(smem + 8192);        // 4 KB
    float* yb = (float*)smem;             // 64 x 66 f32 (union)

    const int tid = threadIdx.x;
    const int wave = tid >> 6, lane = tid & 63;

    // XCD swizzle: 16 ht-tiles x 8 n per XCD (Xb slice 2 MB fits one L2)
    const int f = blockIdx.y * 16 + blockIdx.x;
    const int xcd = f & 7, idx = f >> 3;
    const int n = xcd * 8 + (idx & 7);
    const int ht = idx >> 3;          // 0..15
    const int h0g = ht * 64;

    const int rloc = wave * 16 + (lane >> 2);  // tile-local staged row 0..63
    const int koff = (lane & 3) * 8;           // f16 elems within 32-k slice
    const f16* gBh = Wh + (size_t)(h0g + rloc) * II + koff;
    const f16* gBl = Wl + (size_t)(h0g + rloc) * II + koff;

    f16* lA = As + wave * 512;
    f16* lBh = Bh + wave * 512;
    f16* lBl = Bl + wave * 512;

    const int wm = wave & 1, wn = wave >> 1;
    const int fr = lane & 15, kq = lane >> 4;

    float p1 = 0.f, a1 = 0.f, p2 = 0.f, a2 = 0.f;  // scan state (tid<64)

    for (int c = 0; c < 8; ++c) {
        const int t0 = c * CT1;
        const int TCe = (TT - t0 < CT1) ? (TT - t0) : CT1;

        int ra = rloc; if (ra > TCe - 1) ra = TCe - 1;
        const f16* gA = Xb + ((size_t)n * TT + t0 + ra) * II + koff;

        f32x4 acc[2][2] = {};
        for (int kk = 0; kk < 8; ++kk) {
            const int ko = kk * 32;
            gl2lds16(gA + ko, lA);
            gl2lds16(gBh + ko, lBh);
            gl2lds16(gBl + ko, lBl);
            __syncthreads();

            f16x8 av[2], bhv[2], blv[2];
#pragma unroll
            for (int i = 0; i < 2; ++i) {
                av[i]  = *(const f16x8*)(As + (wm * 32 + i * 16 + fr) * 32 + kq * 8);
                bhv[i] = *(const f16x8*)(Bh + (wn * 32 + i * 16 + fr) * 32 + kq * 8);
                blv[i] = *(const f16x8*)(Bl + (wn * 32 + i * 16 + fr) * 32 + kq * 8);
            }
#pragma unroll
            for (int i = 0; i < 2; ++i)
#pragma unroll
                for (int j = 0; j < 2; ++j) {
                    acc[i][j] = __builtin_amdgcn_mfma_f32_16x16x32_f16(av[i], bhv[j], acc[i][j], 0, 0, 0);
                    acc[i][j] = __builtin_amdgcn_mfma_f32_16x16x32_f16(av[i], blv[j], acc[i][j], 0, 0, 0);
                }
            __syncthreads();
        }

        // epilogue: acc -> yb (t-major, stride 66 words)
#pragma unroll
        for (int i = 0; i < 2; ++i)
#pragma unroll
            for (int j = 0; j < 2; ++j) {
                int tr = wm * 32 + i * 16 + kq * 4;
                int hc = wn * 32 + j * 16 + fr;
#pragma unroll
                for (int r = 0; r < 4; ++r)
                    yb[(tr + r) * 66 + hc] = acc[i][j][r];
            }
        __syncthreads();

        // sequential scan over the chunk; 8-deep LDS prefetch ring
        if (tid < 64) {
            float rb_[8];
#pragma unroll
            for (int j = 0; j < 8; ++j) rb_[j] = yb[j * 66 + tid];
            int t = 0;
            for (; t + 8 <= TCe; t += 8) {
#pragma unroll
                for (int j = 0; j < 8; ++j) {
                    float xv = rb_[j];
                    int tn = t + j + 8;
                    rb_[j] = (tn < TCe) ? yb[tn * 66 + tid] : 0.f;
                    a1 = D_SR * (a1 + p1);
                    p1 = D_SR * p1 + xv;
                    float ut = C_SR * a1;
                    a2 = D_RF * (a2 + p2);
                    float u = ut + C_RF * a2;
                    float s = (u >= THETA) ? 1.0f : 0.0f;
                    p2 = D_RF * p2 + REFS * s;
                    yb[(t + j) * 66 + tid] = s;
                }
            }
            int rem = TCe - t;
#pragma unroll
            for (int j = 0; j < 8; ++j) {
                if (j < rem) {
                    float xv = rb_[j];
                    a1 = D_SR * (a1 + p1);
                    p1 = D_SR * p1 + xv;
                    float ut = C_SR * a1;
                    a2 = D_RF * (a2 + p2);
                    float u = ut + C_RF * a2;
                    float s = (u >= THETA) ? 1.0f : 0.0f;
                    p2 = D_RF * p2 + REFS * s;
                    yb[(t + j) * 66 + tid] = s;
                }
            }
        }
        __syncthreads();

        // pack f16 -> s1b [n*t][H]; 2048 f16x2 pairs / 256 thr = 8 reps
#pragma unroll
        for (int rep = 0; rep < 8; ++rep) {
            int e = rep * 256 + tid;
            int row = e >> 5, cp = e & 31;
            if (row < TCe) {
                float v0 = yb[row * 66 + 2 * cp];
                float v1 = yb[row * 66 + 2 * cp + 1];
                f16x2 h2 = {(f16)v0, (f16)v1};
                *(f16x2*)(S1 + ((size_t)n * TT + t0 + row) * HH + h0g + 2 * cp) = h2;
            }
        }
        __syncthreads();
    }
}

// ---------------- GEMM2 (MFMA, split-f16): y2 = s1b * W2p^T -----------------
__launch_bounds__(256)
__global__ void gemm2_mfma(const f16* __restrict__ S1, const f16* __restrict__ W2h,
                           const f16* __restrict__ W2l, float* __restrict__ Y2) {
    __shared__ __align__(16) f16 As[128 * 32];
    __shared__ __align__(16) f16 Bh[32 * 32];
    __shared__ __align__(16) f16 Bl[32 * 32];

    const int tid = threadIdx.x;
    const int wave = tid >> 6, lane = tid & 63;
    const int m0 = blockIdx.x * 128;

    const f16* gA0 = S1 + (size_t)(m0 + wave * 32 + (lane >> 2)) * HH + (lane & 3) * 8;
    const f16* gA1 = gA0 + (size_t)16 * HH;
    const f16* gB = (wave < 2 ? W2h : W2l) + (size_t)((wave & 1) * 16 + (lane >> 2)) * HH + (lane & 3) * 8;

    f16* lA0 = As + (wave * 32) * 32;
    f16* lA1 = lA0 + 16 * 32;
    f16* lB = (wave < 2 ? Bh : Bl) + ((wave & 1) * 16) * 32;

    f32x4 acc[2][2] = {};
    const int fr = lane & 15, kq = lane >> 4;

    for (int kk = 0; kk < HH / 32; ++kk) {
        const int ko = kk * 32;
        gl2lds16(gA0 + ko, lA0);
        gl2lds16(gA1 + ko, lA1);
        gl2lds16(gB + ko, lB);
        __syncthreads();

        f16x8 a[2], bh[2], bl[2];
#pragma unroll
        for (int i = 0; i < 2; ++i) {
            a[i]  = *(const f16x8*)(As + (wave * 32 + i * 16 + fr) * 32 + kq * 8);
            bh[i] = *(const f16x8*)(Bh + (i * 16 + fr) * 32 + kq * 8);
            bl[i] = *(const f16x8*)(Bl + (i * 16 + fr) * 32 + kq * 8);
        }
#pragma unroll
        for (int i = 0; i < 2; ++i)
#pragma unroll
            for (int j = 0; j < 2; ++j) {
                acc[i][j] = __builtin_amdgcn_mfma_f32_16x16x32_f16(a[i], bh[j], acc[i][j], 0, 0, 0);
                acc[i][j] = __builtin_amdgcn_mfma_f32_16x16x32_f16(a[i], bl[j], acc[i][j], 0, 0, 0);
            }
        __syncthreads();
    }

#pragma unroll
    for (int i = 0; i < 2; ++i)
#pragma unroll
        for (int j = 0; j < 2; ++j) {
            int rbase = m0 + wave * 32 + i * 16 + kq * 4;
            int cc = j * 16 + fr;
            float* p = Y2 + (size_t)rbase * 32 + cc;
#pragma unroll
            for (int r = 0; r < 4; ++r)
                p[(size_t)r * 32] = acc[i][j][r];
        }
}

// ---------------- scan2: y2 [N*T][32] f32 -> out [N][O][T] ------------------
#define PF2 16
__launch_bounds__(64)
__global__ void scan2_k(const float* __restrict__ Y2, float* __restrict__ Out) {
    __shared__ float sb[OO * TT];
    const int n = blockIdx.x, lane = threadIdx.x;
    const float* y = Y2 + (size_t)n * TT * 32;
    const bool act = (lane < 32);

    float p1 = 0.f, a1 = 0.f, p2 = 0.f, a2 = 0.f;
    float buf[PF2];
#pragma unroll
    for (int j = 0; j < PF2; ++j) buf[j] = act ? y[j * 32 + lane] : 0.f;

    int t = 0;
    for (; t + PF2 <= TT; t += PF2) {
#pragma unroll
        for (int j = 0; j < PF2; ++j) {
            float x = buf[j];
            buf[j] = (act && t + j + PF2 < TT) ? y[(t + j + PF2) * 32 + lane] : 0.f;
            a1 = D_SR * (a1 + p1);
            p1 = D_SR * p1 + x;
            float ut = C_SR * a1;
            a2 = D_RF * (a2 + p2);
            float u = ut + C_RF * a2;
            float s = (u >= THETA) ? 1.0f : 0.0f;
            p2 = D_RF * p2 + REFS * s;
            if (lane < OO) sb[lane * TT + t + j] = s;
        }
    }
#pragma unroll
    for (int j = 0; j < PF2; ++j) {
        if (t + j < TT) {
            float x = buf[j];
            a1 = D_SR * (a1 + p1);
            p1 = D_SR * p1 + x;
            float ut = C_SR * a1;
            a2 = D_RF * (a2 + p2);
            float u = ut + C_RF * a2;
            float s = (u >= THETA) ? 1.0f : 0.0f;
            p2 = D_RF * p2 + REFS * s;
            if (lane < OO) sb[lane * TT + t + j] = s;
        }
    }
    __syncthreads();
    float* on = Out + (size_t)n * OO * TT;
    for (int e = lane; e < OO * TT; e += 64) on[e] = sb[e];
}

extern "C" void kernel_launch(void* const* d_in, const int* in_sizes, int n_in,
                              void* d_out, int out_size, void* d_ws, size_t ws_size,
                              hipStream_t stream) {
    const float* X  = (const float*)d_in[0];
    const float* W1 = (const float*)d_in[1];
    const float* W2 = (const float*)d_in[2];
    float* out = (float*)d_out;

    const size_t s_s1 = (size_t)NN * TT * HH * 2;   // 65,536,000
    const size_t s_Xb = (size_t)NN * TT * II * 2;   // 16,384,000
    const size_t s_W  = (size_t)HH * II * 2;        //    524,288 (x2)
    const size_t s_W2 = (size_t)32 * HH * 2;        //     65,536 (x2)
    // + y2 4,096,000 => ~87 MB total

    char* w = (char*)d_ws;
    f16*   s1b = (f16*)w;  w += s_s1;
    f16*   Xb  = (f16*)w;  w += s_Xb;
    f16*   W1h = (f16*)w;  w += s_W;
    f16*   W1l = (f16*)w;  w += s_W;
    f16*   W2h = (f16*)w;  w += s_W2;
    f16*   W2l = (f16*)w;  w += s_W2;
    float* y2  = (float*)w;

    prep_x<<<dim3(8, 4, NN), 256, 0, stream>>>(X, Xb);
    prep_w1<<<(HH * II) / 256, 256, 0, stream>>>(W1, W1h, W1l);
    prep_w2<<<(32 * HH) / 256, 256, 0, stream>>>(W2, W2h, W2l);

    gemm1_scan1<<<dim3(16, NN), 256, 0, stream>>>(Xb, W1h, W1l, s1b);

    gemm2_mfma<<<(NN * TT) / 128, 256, 0, stream>>>(s1b, W2h, W2l, y2);
    scan2_k<<<NN, 64, 0, stream>>>(y2, out);
}

// Round 8
// 212.288 us; speedup vs baseline: 1.3396x; 1.0522x over previous
//
#include <hip/hip_runtime.h>

// SNN forward: [GEMM1+scan1 fused, 128x128 tiles, dbuf K-loop] -> GEMM2 -> scan2
// f16 split-2: W = hi + lo (both f16), residual ~2^-24 => fp32-grade MFMA.
// X and spikes are exact in f16.
// K-loops are 2-deep LDS double-buffered with ONE barrier per iter: loads for
// iter k+1 are issued right after the barrier that guarantees buf[k]'s DMA
// landed, so each load has a full MFMA phase in flight before its drain.

#define NN 64
#define II 256
#define HH 1024
#define OO 18
#define TT 500

#define D_SR 0.9048374180359595f   // exp(-1/10)
#define C_SR 0.27182818284590454f  // e/10
#define D_RF 0.36787944117144233f  // exp(-1)
#define C_RF 2.718281828459045f    // e
#define THETA 10.0f
#define REFS (-20.0f)

typedef _Float16 f16;
typedef _Float16 f16x2 __attribute__((ext_vector_type(2)));
typedef _Float16 f16x8 __attribute__((ext_vector_type(8)));
typedef float f32x4 __attribute__((ext_vector_type(4)));

__device__ __forceinline__ void gl2lds16(const void* g, void* l) {
    __builtin_amdgcn_global_load_lds(
        (const __attribute__((address_space(1))) void*)g,
        (__attribute__((address_space(3))) void*)l, 16, 0, 0);
}

// ---------------- prep: X [N][I][T] f32 -> Xb [N*T][I] f16 (transpose) -----
__launch_bounds__(256)
__global__ void prep_x(const float* __restrict__ X, f16* __restrict__ Xb) {
    __shared__ float tile[64][65];
    const int n = blockIdx.z, i0 = blockIdx.y * 64, t0 = blockIdx.x * 64;
    const int tx = threadIdx.x & 63, q = threadIdx.x >> 6;
    const float* Xn = X + (size_t)n * II * TT;
#pragma unroll 4
    for (int j = 0; j < 16; ++j) {
        int il = j * 4 + q;
        int t = t0 + tx;
        tile[il][tx] = (t < TT) ? Xn[(size_t)(i0 + il) * TT + t] : 0.f;
    }
    __syncthreads();
#pragma unroll 4
    for (int j = 0; j < 16; ++j) {
        int tl = j * 4 + q;
        int t = t0 + tl;
        if (t < TT)
            Xb[((size_t)n * TT + t) * II + i0 + tx] = (f16)tile[tx][tl];
    }
}

// ---------------- prep: W1 -> f16 hi/lo [H][I] ------------------------------
__launch_bounds__(256)
__global__ void prep_w1(const float* __restrict__ W1, f16* __restrict__ Wh,
                        f16* __restrict__ Wl) {
    int idx = blockIdx.x * 256 + threadIdx.x;
    float w = W1[idx];
    f16 h = (f16)w;
    f16 l = (f16)(w - (float)h);
    Wh[idx] = h;
    Wl[idx] = l;
}

// ---------------- prep: W2 -> f16 hi/lo [32 padded][H] ----------------------
__launch_bounds__(256)
__global__ void prep_w2(const float* __restrict__ W2, f16* __restrict__ Wh,
                        f16* __restrict__ Wl) {
    int idx = blockIdx.x * 256 + threadIdx.x;
    int o = idx >> 10;
    float w = (o < OO) ? W2[idx] : 0.f;
    f16 h = (f16)w;
    f16 l = (f16)(w - (float)h);
    Wh[idx] = h;
    Wl[idx] = l;
}

// ---------------- FUSED layer 1: 128x128 tile, dbuf K-loop ------------------
// grid (8, 64), 256 thr. Per block: 4 t-chunks of 128.
// Chunk: prologue loads iter0 -> buf0; 8 K-iters [barrier; issue k+1 -> buf^;
// ds_read+MFMA buf], then epilogue->yb, scan (tid<128), pack -> s1.
// LDS: yb 128x132 f32 = 67.6 KB, staging dbuf (2x24 KB) unioned at its base.
__launch_bounds__(256)
__global__ void gemm1_scan1(const f16* __restrict__ Xb, const f16* __restrict__ Wh,
                            const f16* __restrict__ Wl, f16* __restrict__ S1) {
    __shared__ __align__(16) char smem[128 * 132 * 4];  // 67,584 B
    float* yb = (float*)smem;

    const int tid = threadIdx.x;
    const int wave = tid >> 6, lane = tid & 63;

    // XCD swizzle: the 8 h-tiles of one n share an XCD
    const int f = blockIdx.y * 8 + blockIdx.x;
    const int x = f & 7, g = f >> 3;
    const int n = x * 8 + (g & 7);
    const int ht = g >> 3;
    const int h0g = ht * 128;

    const int rbl = wave * 32 + (lane >> 2);   // staged local row (A rows 0..127)
    const int koff = (lane & 3) * 8;
    const f16* gBh0 = Wh + (size_t)(h0g + rbl) * II + koff;
    const f16* gBl0 = Wl + (size_t)(h0g + rbl) * II + koff;

    const int wm = wave & 1, wn = wave >> 1;
    const int fr = lane & 15, kq = lane >> 4;

    float p1 = 0.f, a1 = 0.f, p2 = 0.f, a2 = 0.f;  // scan state (tid<128)

    for (int c = 0; c < 4; ++c) {
        const int t0 = c * 128;
        const int TCe = (TT - t0 < 128) ? (TT - t0) : 128;

        int r0 = rbl;      if (r0 > TCe - 1) r0 = TCe - 1;
        int r1 = rbl + 16; if (r1 > TCe - 1) r1 = TCe - 1;
        const f16* gA0 = Xb + ((size_t)n * TT + t0 + r0) * II + koff;
        const f16* gA1 = Xb + ((size_t)n * TT + t0 + r1) * II + koff;

        auto stage = [&](int kk2, int b) {
            f16* As_b = (f16*)(smem + b * 24576);
            f16* Bh_b = As_b + 4096;
            f16* Bl_b = As_b + 8192;
            const int ko = kk2 * 32;
            gl2lds16(gA0 + ko, As_b + wave * 1024);
            gl2lds16(gA1 + ko, As_b + wave * 1024 + 512);
            gl2lds16(gBh0 + ko, Bh_b + wave * 1024);
            gl2lds16(gBh0 + 16 * II + ko, Bh_b + wave * 1024 + 512);
            gl2lds16(gBl0 + ko, Bl_b + wave * 1024);
            gl2lds16(gBl0 + 16 * II + ko, Bl_b + wave * 1024 + 512);
        };

        stage(0, 0);  // prologue (previous pack barrier protects yb region)

        f32x4 acc[4][4] = {};
        for (int kk = 0; kk < 8; ++kk) {
            __syncthreads();                 // buf[kk&1] DMA drained here
            if (kk < 7) stage(kk + 1, (kk + 1) & 1);

            const f16* As_b = (const f16*)(smem + (kk & 1) * 24576);
            const f16* Bh_b = As_b + 4096;
            const f16* Bl_b = As_b + 8192;

            f16x8 av[4], bhv[4], blv[4];
#pragma unroll
            for (int i = 0; i < 4; ++i) {
                av[i]  = *(const f16x8*)(As_b + (wm * 64 + i * 16 + fr) * 32 + kq * 8);
                bhv[i] = *(const f16x8*)(Bh_b + (wn * 64 + i * 16 + fr) * 32 + kq * 8);
                blv[i] = *(const f16x8*)(Bl_b + (wn * 64 + i * 16 + fr) * 32 + kq * 8);
            }
#pragma unroll
            for (int i = 0; i < 4; ++i)
#pragma unroll
                for (int j = 0; j < 4; ++j) {
                    acc[i][j] = __builtin_amdgcn_mfma_f32_16x16x32_f16(av[i], bhv[j], acc[i][j], 0, 0, 0);
                    acc[i][j] = __builtin_amdgcn_mfma_f32_16x16x32_f16(av[i], blv[j], acc[i][j], 0, 0, 0);
                }
        }
        __syncthreads();  // all reads done before epilogue overwrites staging

        // epilogue: acc -> yb (t-major, stride 132)
#pragma unroll
        for (int i = 0; i < 4; ++i)
#pragma unroll
            for (int j = 0; j < 4; ++j) {
                int tr = wm * 64 + i * 16 + kq * 4;
                int hc = wn * 64 + j * 16 + fr;
#pragma unroll
                for (int r = 0; r < 4; ++r)
                    yb[(tr + r) * 132 + hc] = acc[i][j][r];
            }
        __syncthreads();

        // sequential scan; 8-deep LDS prefetch ring
        if (tid < 128) {
            float rb_[8];
#pragma unroll
            for (int j = 0; j < 8; ++j) rb_[j] = yb[j * 132 + tid];
            int t = 0;
            for (; t + 8 <= TCe; t += 8) {
#pragma unroll
                for (int j = 0; j < 8; ++j) {
                    float xv = rb_[j];
                    int tn = t + j + 8;
                    rb_[j] = (tn < TCe) ? yb[tn * 132 + tid] : 0.f;
                    a1 = D_SR * (a1 + p1);
                    p1 = D_SR * p1 + xv;
                    float ut = C_SR * a1;
                    a2 = D_RF * (a2 + p2);
                    float u = ut + C_RF * a2;
                    float s = (u >= THETA) ? 1.0f : 0.0f;
                    p2 = D_RF * p2 + REFS * s;
                    yb[(t + j) * 132 + tid] = s;
                }
            }
            int rem = TCe - t;
#pragma unroll
            for (int j = 0; j < 8; ++j) {
                if (j < rem) {
                    float xv = rb_[j];
                    a1 = D_SR * (a1 + p1);
                    p1 = D_SR * p1 + xv;
                    float ut = C_SR * a1;
                    a2 = D_RF * (a2 + p2);
                    float u = ut + C_RF * a2;
                    float s = (u >= THETA) ? 1.0f : 0.0f;
                    p2 = D_RF * p2 + REFS * s;
                    yb[(t + j) * 132 + tid] = s;
                }
            }
        }
        __syncthreads();

        // pack f16 -> s1b [n*t][H]
        const int rowq = tid >> 6;
#pragma unroll 4
        for (int pass = 0; pass < 32; ++pass) {
            int row = pass * 4 + rowq;
            if (row < TCe) {
                float v0 = yb[row * 132 + 2 * lane];
                float v1 = yb[row * 132 + 2 * lane + 1];
                f16x2 h2 = {(f16)v0, (f16)v1};
                *(f16x2*)(S1 + ((size_t)n * TT + t0 + row) * HH + h0g + 2 * lane) = h2;
            }
        }
        __syncthreads();
    }
}

// ---------------- GEMM2 (MFMA, split-f16, dbuf K-loop) ----------------------
// grid 250; 256 thr; tile 128 m x 32 o; K=1024, BK=32.
__launch_bounds__(256)
__global__ void gemm2_mfma(const f16* __restrict__ S1, const f16* __restrict__ W2h,
                           const f16* __restrict__ W2l, float* __restrict__ Y2) {
    __shared__ __align__(16) f16 As[2][128 * 32];  // 2 x 8 KB
    __shared__ __align__(16) f16 Bh[2][32 * 32];   // 2 x 2 KB
    __shared__ __align__(16) f16 Bl[2][32 * 32];   // 2 x 2 KB

    const int tid = threadIdx.x;
    const int wave = tid >> 6, lane = tid & 63;
    const int m0 = blockIdx.x * 128;
    const int fr = lane & 15, kq = lane >> 4;

    const f16* gA0 = S1 + (size_t)(m0 + wave * 32 + (lane >> 2)) * HH + (lane & 3) * 8;
    const f16* gA1 = gA0 + (size_t)16 * HH;
    const f16* gB = (wave < 2 ? W2h : W2l) + (size_t)((wave & 1) * 16 + (lane >> 2)) * HH + (lane & 3) * 8;

    auto stage = [&](int kk2, int b) {
        const int ko = kk2 * 32;
        gl2lds16(gA0 + ko, &As[b][wave * 1024]);
        gl2lds16(gA1 + ko, &As[b][wave * 1024 + 512]);
        gl2lds16(gB + ko, (wave < 2 ? &Bh[b][0] : &Bl[b][0]) + (wave & 1) * 512);
    };

    stage(0, 0);

    f32x4 acc[2][2] = {};
    for (int kk = 0; kk < HH / 32; ++kk) {
        __syncthreads();
        if (kk < HH / 32 - 1) stage(kk + 1, (kk + 1) & 1);
        const int b = kk & 1;

        f16x8 a[2], bh[2], bl[2];
#pragma unroll
        for (int i = 0; i < 2; ++i) {
            a[i]  = *(const f16x8*)(&As[b][(wave * 32 + i * 16 + fr) * 32 + kq * 8]);
            bh[i] = *(const f16x8*)(&Bh[b][(i * 16 + fr) * 32 + kq * 8]);
            bl[i] = *(const f16x8*)(&Bl[b][(i * 16 + fr) * 32 + kq * 8]);
        }
#pragma unroll
        for (int i = 0; i < 2; ++i)
#pragma unroll
            for (int j = 0; j < 2; ++j) {
                acc[i][j] = __builtin_amdgcn_mfma_f32_16x16x32_f16(a[i], bh[j], acc[i][j], 0, 0, 0);
                acc[i][j] = __builtin_amdgcn_mfma_f32_16x16x32_f16(a[i], bl[j], acc[i][j], 0, 0, 0);
            }
    }

#pragma unroll
    for (int i = 0; i < 2; ++i)
#pragma unroll
        for (int j = 0; j < 2; ++j) {
            int rbase = m0 + wave * 32 + i * 16 + kq * 4;
            int cc = j * 16 + fr;
            float* p = Y2 + (size_t)rbase * 32 + cc;
#pragma unroll
            for (int r = 0; r < 4; ++r)
                p[(size_t)r * 32] = acc[i][j][r];
        }
}

// ---------------- scan2: y2 [N*T][32] f32 -> out [N][O][T] ------------------
#define PF2 16
__launch_bounds__(64)
__global__ void scan2_k(const float* __restrict__ Y2, float* __restrict__ Out) {
    __shared__ float sb[OO * TT];
    const int n = blockIdx.x, lane = threadIdx.x;
    const float* y = Y2 + (size_t)n * TT * 32;
    const bool act = (lane < 32);

    float p1 = 0.f, a1 = 0.f, p2 = 0.f, a2 = 0.f;
    float buf[PF2];
#pragma unroll
    for (int j = 0; j < PF2; ++j) buf[j] = act ? y[j * 32 + lane] : 0.f;

    int t = 0;
    for (; t + PF2 <= TT; t += PF2) {
#pragma unroll
        for (int j = 0; j < PF2; ++j) {
            float x = buf[j];
            buf[j] = (act && t + j + PF2 < TT) ? y[(t + j + PF2) * 32 + lane] : 0.f;
            a1 = D_SR * (a1 + p1);
            p1 = D_SR * p1 + x;
            float ut = C_SR * a1;
            a2 = D_RF * (a2 + p2);
            float u = ut + C_RF * a2;
            float s = (u >= THETA) ? 1.0f : 0.0f;
            p2 = D_RF * p2 + REFS * s;
            if (lane < OO) sb[lane * TT + t + j] = s;
        }
    }
#pragma unroll
    for (int j = 0; j < PF2; ++j) {
        if (t + j < TT) {
            float x = buf[j];
            a1 = D_SR * (a1 + p1);
            p1 = D_SR * p1 + x;
            float ut = C_SR * a1;
            a2 = D_RF * (a2 + p2);
            float u = ut + C_RF * a2;
            float s = (u >= THETA) ? 1.0f : 0.0f;
            p2 = D_RF * p2 + REFS * s;
            if (lane < OO) sb[lane * TT + t + j] = s;
        }
    }
    __syncthreads();
    float* on = Out + (size_t)n * OO * TT;
    for (int e = lane; e < OO * TT; e += 64) on[e] = sb[e];
}

extern "C" void kernel_launch(void* const* d_in, const int* in_sizes, int n_in,
                              void* d_out, int out_size, void* d_ws, size_t ws_size,
                              hipStream_t stream) {
    const float* X  = (const float*)d_in[0];
    const float* W1 = (const float*)d_in[1];
    const float* W2 = (const float*)d_in[2];
    float* out = (float*)d_out;

    const size_t s_s1 = (size_t)NN * TT * HH * 2;   // 65,536,000
    const size_t s_Xb = (size_t)NN * TT * II * 2;   // 16,384,000
    const size_t s_W  = (size_t)HH * II * 2;        //    524,288 (x2)
    const size_t s_W2 = (size_t)32 * HH * 2;        //     65,536 (x2)

    char* w = (char*)d_ws;
    f16*   s1b = (f16*)w;  w += s_s1;
    f16*   Xb  = (f16*)w;  w += s_Xb;
    f16*   W1h = (f16*)w;  w += s_W;
    f16*   W1l = (f16*)w;  w += s_W;
    f16*   W2h = (f16*)w;  w += s_W2;
    f16*   W2l = (f16*)w;  w += s_W2;
    float* y2  = (float*)w;

    prep_x<<<dim3(8, 4, NN), 256, 0, stream>>>(X, Xb);
    prep_w1<<<(HH * II) / 256, 256, 0, stream>>>(W1, W1h, W1l);
    prep_w2<<<(32 * HH) / 256, 256, 0, stream>>>(W2, W2h, W2l);

    gemm1_scan1<<<dim3(8, NN), 256, 0, stream>>>(Xb, W1h, W1l, s1b);

    gemm2_mfma<<<(NN * TT) / 128, 256, 0, stream>>>(s1b, W2h, W2l, y2);
    scan2_k<<<NN, 64, 0, stream>>>(y2, out);
}